// Round 5
// baseline (2805.606 us; speedup 1.0000x reference)
//
#include <hip/hip_runtime.h>
#include <hip/hip_bf16.h>
#include <cstdint>
#include <cstddef>

#define TTOK   4096
#define DIM_   2048
#define INTER_ 1408
#define NEXP   16
#define SINTER_ 2816
#define BM 128
#define BN 128
#define BK 32
#define MAXROWS (TTOK*2 + NEXP*BM)      /* 10240 padded routed slots */
#define MAXMT   (TTOK*2/BM + NEXP)      /* 80 worst-case M tiles */

typedef unsigned short u16;
typedef __attribute__((ext_vector_type(8))) short short8;
typedef __attribute__((ext_vector_type(4))) float f32x4;

#define AS3P(p) ((__attribute__((address_space(3))) void*)(p))
#define AS1P(p) ((const __attribute__((address_space(1))) void*)(p))

__device__ __forceinline__ void gll16(const void* g, void* l) {
    __builtin_amdgcn_global_load_lds(AS1P(g), AS3P(l), 16, 0, 0);
}

__device__ __forceinline__ u16 f2bf(float f) {
    __hip_bfloat16 h = __float2bfloat16(f);
    union { __hip_bfloat16 h; u16 u; } c; c.h = h; return c.u;
}

__device__ __forceinline__ unsigned pk2(float a, float b) {
    unsigned r;
    asm("v_cvt_pk_bf16_f32 %0, %1, %2" : "=v"(r) : "v"(a), "v"(b));
    return r;
}

// two float4 (8 consecutive k-floats) -> short8 bf16 frag
__device__ __forceinline__ short8 cvt8(float4 q0, float4 q1) {
    union { int4 i; short8 s; } u;
    u.i = make_int4((int)pk2(q0.x, q0.y), (int)pk2(q0.z, q0.w),
                    (int)pk2(q1.x, q1.y), (int)pk2(q1.z, q1.w));
    return u.s;
}

__device__ __forceinline__ int4 pack8(float4 a, float4 b) {
    int4 r;
    r.x = (int)pk2(a.x, a.y);
    r.y = (int)pk2(a.z, a.w);
    r.z = (int)pk2(b.x, b.y);
    r.w = (int)pk2(b.z, b.w);
    return r;
}

// ---------------- small kernels ----------------

// misc layout (ints): [0..16) counts, [16..32) fill, [32..48) base,
//                     [48..128) tile_expert, [128..208) tile_row0
__global__ void init_kernel(int* perm_rt, float* pw_rt, int* perm_sh, int* misc, int* zrow) {
    int i = blockIdx.x * 256 + threadIdx.x;
    if (i < MAXROWS) { perm_rt[i] = -1; pw_rt[i] = 0.f; }
    if (i < TTOK)    perm_sh[i] = i;
    if (i < 32)      misc[i] = 0;
    if (i < 1024)    zrow[i] = 0;      // 4 KB zero page
}

// f32 -> bf16, 8 elems/thread, grid-stride (used for x only)
__global__ void cvt_kernel(const float* __restrict__ s, u16* __restrict__ d, int n8) {
    int stride = gridDim.x * 256;
    for (int i = blockIdx.x * 256 + threadIdx.x; i < n8; i += stride) {
        const float4* s4 = (const float4*)(s + (size_t)i * 8);
        float4 a = s4[0], b = s4[1];
        *(int4*)(d + (size_t)i * 8) = pack8(a, b);
    }
}

__global__ void gate_kernel(const float* __restrict__ x, const float* __restrict__ gw,
                            int* __restrict__ topi, float* __restrict__ topw,
                            int* __restrict__ misc) {
    int t = blockIdx.x;
    int lane = threadIdx.x;
    const float* xr = x + (size_t)t * DIM_;
    float acc[NEXP];
#pragma unroll
    for (int e = 0; e < NEXP; e++) acc[e] = 0.f;
#pragma unroll
    for (int i = 0; i < 8; i++) {
        int k = i * 256 + lane * 4;
        float4 xv = *(const float4*)(xr + k);
#pragma unroll
        for (int e = 0; e < NEXP; e++) {
            float4 gv = *(const float4*)(gw + (size_t)e * DIM_ + k);
            acc[e] += xv.x * gv.x + xv.y * gv.y + xv.z * gv.z + xv.w * gv.w;
        }
    }
#pragma unroll
    for (int e = 0; e < NEXP; e++) {
        float v = acc[e];
        for (int off = 32; off > 0; off >>= 1) v += __shfl_down(v, off);
        acc[e] = v;
    }
    if (lane == 0) {
        float m = acc[0];
#pragma unroll
        for (int e = 1; e < NEXP; e++) m = fmaxf(m, acc[e]);
        float p[NEXP]; float s = 0.f;
#pragma unroll
        for (int e = 0; e < NEXP; e++) { p[e] = __expf(acc[e] - m); s += p[e]; }
        int i0 = 0; float v0 = p[0];
#pragma unroll
        for (int e = 1; e < NEXP; e++) if (p[e] > v0) { v0 = p[e]; i0 = e; }
        int i1 = -1; float v1 = -1.f;
#pragma unroll
        for (int e = 0; e < NEXP; e++) if (e != i0 && p[e] > v1) { v1 = p[e]; i1 = e; }
        float inv = 1.f / s;
        topi[2 * t] = i0; topi[2 * t + 1] = i1;
        topw[2 * t] = v0 * inv; topw[2 * t + 1] = v1 * inv;
        atomicAdd(&misc[i0], 1);
        atomicAdd(&misc[i1], 1);
    }
}

__global__ void scan_kernel(int* misc) {
    int* counts = misc;
    int* base   = misc + 32;
    int* te     = misc + 48;
    int* tr     = misc + 128;
    int b = 0, tt = 0;
    for (int e = 0; e < NEXP; e++) {
        int c = counts[e];
        int nt = (c + BM - 1) >> 7;
        base[e] = b;
        for (int i = 0; i < nt; i++) { te[tt] = e; tr[tt] = b + i * BM; tt++; }
        b += nt * BM;
    }
    for (int i = tt; i < MAXMT; i++) te[i] = -1;
}

__global__ void scatter_kernel(const int* __restrict__ topi, const float* __restrict__ topw,
                               int* __restrict__ misc, int* __restrict__ perm,
                               float* __restrict__ pw) {
    int t = blockIdx.x * 256 + threadIdx.x;
    if (t >= TTOK) return;
    int* fill = misc + 16;
    int* base = misc + 32;
#pragma unroll
    for (int k = 0; k < 2; k++) {
        int e = topi[2 * t + k];
        int pos = base[e] + atomicAdd(&fill[e], 1);
        perm[pos] = t;
        pw[pos] = topw[2 * t + k];
    }
}

// ---------------- GEMM kernels ----------------
// C[M,N] = A[M,K] @ B[N,K]^T ; A bf16 in LDS, B **f32 in LDS** (gll16-staged,
// converted to bf16 on fragment read via v_cvt_pk_bf16_f32). No weight cvt pass.
// XOR swizzles (both-sides: pre-swizzled per-lane GLOBAL src + swizzled read):
//   A bf16 [128][32]: src chunk (l&3)^((l>>3)&3); read chunk kg^((col>>1)&3)
//   B f32  [128][32f]: src chunk (l&7)^(l>>3);    read chunk c^(col&7)
// XCD-chunked jn-major 1D grid (T1).

template<bool GROUPED>
__global__ __launch_bounds__(256, 4) void gemm_h13_k(
    const u16* __restrict__ Xb,
    const float* __restrict__ W1b, const float* __restrict__ W3b,
    u16* __restrict__ H,
    const int* __restrict__ perm,
    const int* __restrict__ te, const int* __restrict__ tr,
    const u16* __restrict__ zrow,
    int N, int K, int nt_m, int chunk)
{
    const int q = (blockIdx.x & 7) * chunk + (blockIdx.x >> 3);
    if (q >= nt_m * (N / BN)) return;
    const int jn = q / nt_m, im = q % nt_m;
    int e, slot0;
    if (GROUPED) { e = te[im]; if (e < 0) return; slot0 = tr[im]; }
    else         { e = 0; slot0 = im * BM; }
    const int n0 = jn * BN;
    const float* W1 = W1b + (size_t)e * N * K;
    const float* W3 = W3b + (size_t)e * N * K;

    __shared__ __align__(16) u16   As[BM * BK];
    __shared__ __align__(16) float B1f[BM * BK];
    __shared__ __align__(16) float B3f[BM * BK];

    const int tid = threadIdx.x;
    const int lane = tid & 63, wid = tid >> 6;
    const int wr = wid >> 1, wc = wid & 1;
    const int col = lane & 15, kg = lane >> 4;

    // ---- A staging: 2 insts/wave, 16 rows each; lane -> row base+(l>>2), swz chunk
    const int aRow = wid * 32 + (lane >> 2);
    const int aCk  = ((lane & 3) ^ ((lane >> 3) & 3)) * 8;   // u16 elems
    const int ta0 = perm[slot0 + aRow];
    const int ta1 = perm[slot0 + aRow + 16];
    const u16* ga0 = (ta0 >= 0 ? Xb + (size_t)ta0 * K : zrow) + aCk;
    const u16* ga1 = (ta1 >= 0 ? Xb + (size_t)ta1 * K : zrow) + aCk;
    u16* la0 = As + (wid * 32) * BK;
    u16* la1 = As + (wid * 32 + 16) * BK;

    // ---- B staging: 4 insts/wave each matrix, 8 rows per inst
    const int bRowL = lane >> 3;                       // row within inst group
    const int bCk   = ((lane & 7) ^ bRowL) * 4;        // float offset in row
    const float* g1 = W1 + (size_t)(n0 + wid * 32 + bRowL) * K + bCk;
    const float* g3 = W3 + (size_t)(n0 + wid * 32 + bRowL) * K + bCk;
    float* lb1 = B1f + (wid * 32) * BK;
    float* lb3 = B3f + (wid * 32) * BK;

    // ---- fragment read constants
    const int aswz = (col >> 1) & 3;
    const int bswz = col & 7;

    f32x4 acc1[4][4] = {};
    f32x4 acc3[4][4] = {};

    for (int k0 = 0; k0 < K; k0 += BK) {
        gll16(ga0 + k0, la0);
        gll16(ga1 + k0, la1);
#pragma unroll
        for (int j = 0; j < 4; j++) {
            gll16(g1 + (size_t)j * 8 * K + k0, lb1 + j * 8 * BK);
            gll16(g3 + (size_t)j * 8 * K + k0, lb3 + j * 8 * BK);
        }
        __syncthreads();

        short8 a[4];
#pragma unroll
        for (int mi = 0; mi < 4; mi++)
            a[mi] = *(const short8*)(As + (wr * 64 + mi * 16 + col) * BK + ((kg ^ aswz) * 8));
#pragma unroll
        for (int ni = 0; ni < 4; ni++) {
            const int rowB = wc * 64 + ni * 16 + col;
            const float* rb1 = B1f + rowB * BK;
            const float* rb3 = B3f + rowB * BK;
            const int c0 = ((kg * 2) ^ bswz) * 4;
            const int c1 = ((kg * 2 + 1) ^ bswz) * 4;
            short8 v1 = cvt8(*(const float4*)(rb1 + c0), *(const float4*)(rb1 + c1));
            short8 v3 = cvt8(*(const float4*)(rb3 + c0), *(const float4*)(rb3 + c1));
#pragma unroll
            for (int mi = 0; mi < 4; mi++) {
                acc1[mi][ni] = __builtin_amdgcn_mfma_f32_16x16x32_bf16(a[mi], v1, acc1[mi][ni], 0, 0, 0);
                acc3[mi][ni] = __builtin_amdgcn_mfma_f32_16x16x32_bf16(a[mi], v3, acc3[mi][ni], 0, 0, 0);
            }
        }
        __syncthreads();
    }

    // epilogue: h = silu(acc1) * acc3, store bf16 (padding rows produce 0)
#pragma unroll
    for (int mi = 0; mi < 4; mi++) {
#pragma unroll
        for (int j = 0; j < 4; j++) {
            int row = slot0 + wr * 64 + mi * 16 + kg * 4 + j;
#pragma unroll
            for (int ni = 0; ni < 4; ni++) {
                float v1 = acc1[mi][ni][j];
                float v3 = acc3[mi][ni][j];
                float hv = v1 / (1.f + __expf(-v1)) * v3;
                int c = n0 + wc * 64 + ni * 16 + col;
                H[(size_t)row * N + c] = f2bf(hv);
            }
        }
    }
}

template<bool ATOMIC>
__global__ __launch_bounds__(256, 4) void gemm_out_k(
    const u16* __restrict__ Hm,
    const float* __restrict__ W2b,
    float* __restrict__ Out,
    const int* __restrict__ perm, const float* __restrict__ pw,
    const int* __restrict__ te, const int* __restrict__ tr,
    int K, int nt_m, int chunk)
{
    const int q = (blockIdx.x & 7) * chunk + (blockIdx.x >> 3);
    if (q >= nt_m * (DIM_ / BN)) return;
    const int jn = q / nt_m, im = q % nt_m;
    int e, slot0;
    if (ATOMIC) { e = te[im]; if (e < 0) return; slot0 = tr[im]; }
    else        { e = 0; slot0 = im * BM; }
    const int n0 = jn * BN;
    const float* W2 = W2b + (size_t)e * DIM_ * K;

    __shared__ __align__(16) u16   As[BM * BK];
    __shared__ __align__(16) float Bf[BM * BK];

    const int tid = threadIdx.x;
    const int lane = tid & 63, wid = tid >> 6;
    const int wr = wid >> 1, wc = wid & 1;
    const int col = lane & 15, kg = lane >> 4;

    const int aRow = wid * 32 + (lane >> 2);
    const int aCk  = ((lane & 3) ^ ((lane >> 3) & 3)) * 8;
    const u16* ga0 = Hm + (size_t)(slot0 + aRow) * K + aCk;
    const u16* ga1 = Hm + (size_t)(slot0 + aRow + 16) * K + aCk;
    u16* la0 = As + (wid * 32) * BK;
    u16* la1 = As + (wid * 32 + 16) * BK;

    const int bRowL = lane >> 3;
    const int bCk   = ((lane & 7) ^ bRowL) * 4;
    const float* g2 = W2 + (size_t)(n0 + wid * 32 + bRowL) * K + bCk;
    float* lb = Bf + (wid * 32) * BK;

    const int aswz = (col >> 1) & 3;
    const int bswz = col & 7;

    f32x4 acc[4][4] = {};

    for (int k0 = 0; k0 < K; k0 += BK) {
        gll16(ga0 + k0, la0);
        gll16(ga1 + k0, la1);
#pragma unroll
        for (int j = 0; j < 4; j++)
            gll16(g2 + (size_t)j * 8 * K + k0, lb + j * 8 * BK);
        __syncthreads();

        short8 a[4];
#pragma unroll
        for (int mi = 0; mi < 4; mi++)
            a[mi] = *(const short8*)(As + (wr * 64 + mi * 16 + col) * BK + ((kg ^ aswz) * 8));
#pragma unroll
        for (int ni = 0; ni < 4; ni++) {
            const int rowB = wc * 64 + ni * 16 + col;
            const float* rb = Bf + rowB * BK;
            const int c0 = ((kg * 2) ^ bswz) * 4;
            const int c1 = ((kg * 2 + 1) ^ bswz) * 4;
            short8 bv = cvt8(*(const float4*)(rb + c0), *(const float4*)(rb + c1));
#pragma unroll
            for (int mi = 0; mi < 4; mi++)
                acc[mi][ni] = __builtin_amdgcn_mfma_f32_16x16x32_bf16(a[mi], bv, acc[mi][ni], 0, 0, 0);
        }
        __syncthreads();
    }

#pragma unroll
    for (int mi = 0; mi < 4; mi++) {
#pragma unroll
        for (int j = 0; j < 4; j++) {
            int rloc = wr * 64 + mi * 16 + kg * 4 + j;
            int slot = slot0 + rloc;
            if (ATOMIC) {
                int token = perm[slot];
                if (token < 0) continue;
                float w = pw[slot];
#pragma unroll
                for (int ni = 0; ni < 4; ni++) {
                    int c = n0 + wc * 64 + ni * 16 + col;
                    atomicAdd(&Out[(size_t)token * DIM_ + c], acc[mi][ni][j] * w);
                }
            } else {
#pragma unroll
                for (int ni = 0; ni < 4; ni++) {
                    int c = n0 + wc * 64 + ni * 16 + col;
                    Out[(size_t)slot * DIM_ + c] = acc[mi][ni][j];
                }
            }
        }
    }
}

// ---------------- launch ----------------

extern "C" void kernel_launch(void* const* d_in, const int* in_sizes, int n_in,
                              void* d_out, int out_size, void* d_ws, size_t ws_size,
                              hipStream_t stream) {
    (void)in_sizes; (void)n_in; (void)out_size; (void)ws_size;
    const float* x   = (const float*)d_in[0];
    const float* gw  = (const float*)d_in[1];
    const float* w1  = (const float*)d_in[2];
    const float* w2  = (const float*)d_in[3];
    const float* w3  = (const float*)d_in[4];
    const float* sw1 = (const float*)d_in[5];
    const float* sw2 = (const float*)d_in[6];
    const float* sw3 = (const float*)d_in[7];
    float* out = (float*)d_out;

    char* ws = (char*)d_ws;
    size_t off = 0;
    auto take = [&](size_t bytes) -> void* {
        void* p = ws + off;
        off += (bytes + 255) & ~(size_t)255;
        return p;
    };
    u16*   xb      = (u16*)take((size_t)TTOK * DIM_ * 2);
    u16*   hbuf    = (u16*)take((size_t)MAXROWS * INTER_ * 2);
    int*   perm_rt = (int*)take((size_t)MAXROWS * 4);
    float* pw_rt   = (float*)take((size_t)MAXROWS * 4);
    int*   perm_sh = (int*)take((size_t)TTOK * 4);
    int*   topi    = (int*)take((size_t)TTOK * 2 * 4);
    float* topw    = (float*)take((size_t)TTOK * 2 * 4);
    int*   misc    = (int*)take(1024);
    int*   zrow    = (int*)take(4096);

    init_kernel<<<MAXROWS / 256, 256, 0, stream>>>(perm_rt, pw_rt, perm_sh, misc, zrow);
    cvt_kernel<<<512, 256, 0, stream>>>(x, xb, TTOK * DIM_ / 8);
    gate_kernel<<<TTOK, 64, 0, stream>>>(x, gw, topi, topw, misc);
    scan_kernel<<<1, 1, 0, stream>>>(misc);
    scatter_kernel<<<TTOK / 256, 256, 0, stream>>>(topi, topw, misc, perm_rt, pw_rt);

    auto grid8 = [](int total) { return ((total + 7) / 8) * 8; };
    auto chunk8 = [](int total) { return (total + 7) / 8; };

    // shared expert
    {
        int total = (TTOK / BM) * (SINTER_ / BN);
        gemm_h13_k<false><<<grid8(total), 256, 0, stream>>>(
            xb, sw1, sw3, hbuf, perm_sh, nullptr, nullptr, (const u16*)zrow,
            SINTER_, DIM_, TTOK / BM, chunk8(total));
    }
    {
        int total = (TTOK / BM) * (DIM_ / BN);
        gemm_out_k<false><<<grid8(total), 256, 0, stream>>>(
            hbuf, sw2, out, nullptr, nullptr, nullptr, nullptr,
            SINTER_, TTOK / BM, chunk8(total));
    }
    // routed experts
    {
        int total = MAXMT * (INTER_ / BN);
        gemm_h13_k<true><<<grid8(total), 256, 0, stream>>>(
            xb, w1, w3, hbuf, perm_rt, misc + 48, misc + 128, (const u16*)zrow,
            INTER_, DIM_, MAXMT, chunk8(total));
    }
    {
        int total = MAXMT * (DIM_ / BN);
        gemm_out_k<true><<<grid8(total), 256, 0, stream>>>(
            hbuf, w2, out, perm_rt, pw_rt, misc + 48, misc + 128,
            INTER_, MAXMT, chunk8(total));
    }
}

// Round 6
// 878.983 us; speedup vs baseline: 3.1919x; 3.1919x over previous
//
#include <hip/hip_runtime.h>
#include <hip/hip_bf16.h>
#include <cstdint>
#include <cstddef>

#define TTOK   4096
#define DIM_   2048
#define INTER_ 1408
#define NEXP   16
#define SINTER_ 2816
#define BM 128
#define BN 128
#define BK 32
#define MAXROWS (TTOK*2 + NEXP*BM)      /* 10240 padded routed slots */
#define MAXMT   (TTOK*2/BM + NEXP)      /* 80 worst-case M tiles */

typedef unsigned short u16;
typedef __attribute__((ext_vector_type(8))) short short8;
typedef __attribute__((ext_vector_type(4))) float f32x4;

#define AS3P(p) ((__attribute__((address_space(3))) void*)(p))
#define AS1P(p) ((const __attribute__((address_space(1))) void*)(p))

__device__ __forceinline__ void gll16(const void* g, void* l) {
    __builtin_amdgcn_global_load_lds(AS1P(g), AS3P(l), 16, 0, 0);
}

__device__ __forceinline__ u16 f2bf(float f) {
    __hip_bfloat16 h = __float2bfloat16(f);
    union { __hip_bfloat16 h; u16 u; } c; c.h = h; return c.u;
}

__device__ __forceinline__ unsigned pk2(float a, float b) {
    unsigned r;
    asm("v_cvt_pk_bf16_f32 %0, %1, %2" : "=v"(r) : "v"(a), "v"(b));
    return r;
}

// two float4 (8 consecutive k-floats) -> short8 bf16 frag
__device__ __forceinline__ short8 cvt8(float4 q0, float4 q1) {
    union { int4 i; short8 s; } u;
    u.i = make_int4((int)pk2(q0.x, q0.y), (int)pk2(q0.z, q0.w),
                    (int)pk2(q1.x, q1.y), (int)pk2(q1.z, q1.w));
    return u.s;
}

__device__ __forceinline__ int4 pack8(float4 a, float4 b) {
    int4 r;
    r.x = (int)pk2(a.x, a.y);
    r.y = (int)pk2(a.z, a.w);
    r.z = (int)pk2(b.x, b.y);
    r.w = (int)pk2(b.z, b.w);
    return r;
}

// ---------------- small kernels ----------------

// misc layout (ints): [0..16) counts, [16..32) fill, [32..48) base,
//                     [48..128) tile_expert, [128..208) tile_row0
__global__ void init_kernel(int* perm_rt, float* pw_rt, int* perm_sh, int* misc, int* zrow) {
    int i = blockIdx.x * 256 + threadIdx.x;
    if (i < MAXROWS) { perm_rt[i] = -1; pw_rt[i] = 0.f; }
    if (i < TTOK)    perm_sh[i] = i;
    if (i < 32)      misc[i] = 0;
    if (i < 1024)    zrow[i] = 0;      // 4 KB zero page
}

// f32 -> bf16, 8 elems/thread, grid-stride (used for x only)
__global__ void cvt_kernel(const float* __restrict__ s, u16* __restrict__ d, int n8) {
    int stride = gridDim.x * 256;
    for (int i = blockIdx.x * 256 + threadIdx.x; i < n8; i += stride) {
        const float4* s4 = (const float4*)(s + (size_t)i * 8);
        float4 a = s4[0], b = s4[1];
        *(int4*)(d + (size_t)i * 8) = pack8(a, b);
    }
}

__global__ void gate_kernel(const float* __restrict__ x, const float* __restrict__ gw,
                            int* __restrict__ topi, float* __restrict__ topw,
                            int* __restrict__ misc) {
    int t = blockIdx.x;
    int lane = threadIdx.x;
    const float* xr = x + (size_t)t * DIM_;
    float acc[NEXP];
#pragma unroll
    for (int e = 0; e < NEXP; e++) acc[e] = 0.f;
#pragma unroll
    for (int i = 0; i < 8; i++) {
        int k = i * 256 + lane * 4;
        float4 xv = *(const float4*)(xr + k);
#pragma unroll
        for (int e = 0; e < NEXP; e++) {
            float4 gv = *(const float4*)(gw + (size_t)e * DIM_ + k);
            acc[e] += xv.x * gv.x + xv.y * gv.y + xv.z * gv.z + xv.w * gv.w;
        }
    }
#pragma unroll
    for (int e = 0; e < NEXP; e++) {
        float v = acc[e];
        for (int off = 32; off > 0; off >>= 1) v += __shfl_down(v, off);
        acc[e] = v;
    }
    if (lane == 0) {
        float m = acc[0];
#pragma unroll
        for (int e = 1; e < NEXP; e++) m = fmaxf(m, acc[e]);
        float p[NEXP]; float s = 0.f;
#pragma unroll
        for (int e = 0; e < NEXP; e++) { p[e] = __expf(acc[e] - m); s += p[e]; }
        int i0 = 0; float v0 = p[0];
#pragma unroll
        for (int e = 1; e < NEXP; e++) if (p[e] > v0) { v0 = p[e]; i0 = e; }
        int i1 = -1; float v1 = -1.f;
#pragma unroll
        for (int e = 0; e < NEXP; e++) if (e != i0 && p[e] > v1) { v1 = p[e]; i1 = e; }
        float inv = 1.f / s;
        topi[2 * t] = i0; topi[2 * t + 1] = i1;
        topw[2 * t] = v0 * inv; topw[2 * t + 1] = v1 * inv;
        atomicAdd(&misc[i0], 1);
        atomicAdd(&misc[i1], 1);
    }
}

__global__ void scan_kernel(int* misc) {
    int* counts = misc;
    int* base   = misc + 32;
    int* te     = misc + 48;
    int* tr     = misc + 128;
    int b = 0, tt = 0;
    for (int e = 0; e < NEXP; e++) {
        int c = counts[e];
        int nt = (c + BM - 1) >> 7;
        base[e] = b;
        for (int i = 0; i < nt; i++) { te[tt] = e; tr[tt] = b + i * BM; tt++; }
        b += nt * BM;
    }
    for (int i = tt; i < MAXMT; i++) te[i] = -1;
}

__global__ void scatter_kernel(const int* __restrict__ topi, const float* __restrict__ topw,
                               int* __restrict__ misc, int* __restrict__ perm,
                               float* __restrict__ pw) {
    int t = blockIdx.x * 256 + threadIdx.x;
    if (t >= TTOK) return;
    int* fill = misc + 16;
    int* base = misc + 32;
#pragma unroll
    for (int k = 0; k < 2; k++) {
        int e = topi[2 * t + k];
        int pos = base[e] + atomicAdd(&fill[e], 1);
        perm[pos] = t;
        pw[pos] = topw[2 * t + k];
    }
}

// ---------------- GEMM kernels ----------------
// C[M,N] = A[M,K] @ B[N,K]^T ; A bf16 in LDS, B f32 in LDS (gll16-staged,
// converted to bf16 on fragment read via v_cvt_pk_bf16_f32). No weight cvt pass.
// XOR swizzles (both-sides: pre-swizzled per-lane GLOBAL src + swizzled read):
//   A bf16 [128][32]: src chunk (l&3)^((l>>3)&3); read chunk kg^((col>>1)&3)
//   B f32  [128][32f]: src chunk (l&7)^(l>>3);    read chunk c^(col&7)
// XCD-chunked jn-major 1D grid (T1).
// NOTE: __launch_bounds__(256,2) is REQUIRED — (256,4) caps VGPR at 128 and
// spills the 128-reg accumulator to scratch (R5: FETCH 2.1GB, 8x slowdown).

template<bool GROUPED>
__global__ __launch_bounds__(256, 2) void gemm_h13_k(
    const u16* __restrict__ Xb,
    const float* __restrict__ W1b, const float* __restrict__ W3b,
    u16* __restrict__ H,
    const int* __restrict__ perm,
    const int* __restrict__ te, const int* __restrict__ tr,
    const u16* __restrict__ zrow,
    int N, int K, int nt_m, int chunk)
{
    const int q = (blockIdx.x & 7) * chunk + (blockIdx.x >> 3);
    if (q >= nt_m * (N / BN)) return;
    const int jn = q / nt_m, im = q % nt_m;
    int e, slot0;
    if (GROUPED) { e = te[im]; if (e < 0) return; slot0 = tr[im]; }
    else         { e = 0; slot0 = im * BM; }
    const int n0 = jn * BN;
    const float* W1 = W1b + (size_t)e * N * K;
    const float* W3 = W3b + (size_t)e * N * K;

    __shared__ __align__(16) u16   As[BM * BK];
    __shared__ __align__(16) float B1f[BM * BK];
    __shared__ __align__(16) float B3f[BM * BK];

    const int tid = threadIdx.x;
    const int lane = tid & 63, wid = tid >> 6;
    const int wr = wid >> 1, wc = wid & 1;
    const int col = lane & 15, kg = lane >> 4;

    // ---- A staging: 2 insts/wave, 16 rows each; lane -> row base+(l>>2), swz chunk
    const int aRow = wid * 32 + (lane >> 2);
    const int aCk  = ((lane & 3) ^ ((lane >> 3) & 3)) * 8;   // u16 elems
    const int ta0 = perm[slot0 + aRow];
    const int ta1 = perm[slot0 + aRow + 16];
    const u16* ga0 = (ta0 >= 0 ? Xb + (size_t)ta0 * K : zrow) + aCk;
    const u16* ga1 = (ta1 >= 0 ? Xb + (size_t)ta1 * K : zrow) + aCk;
    u16* la0 = As + (wid * 32) * BK;
    u16* la1 = As + (wid * 32 + 16) * BK;

    // ---- B staging: 4 insts/wave each matrix, 8 rows per inst
    const int bRowL = lane >> 3;                       // row within inst group
    const int bCk   = ((lane & 7) ^ bRowL) * 4;        // float offset in row
    const float* g1 = W1 + (size_t)(n0 + wid * 32 + bRowL) * K + bCk;
    const float* g3 = W3 + (size_t)(n0 + wid * 32 + bRowL) * K + bCk;
    float* lb1 = B1f + (wid * 32) * BK;
    float* lb3 = B3f + (wid * 32) * BK;

    // ---- fragment read constants
    const int aswz = (col >> 1) & 3;
    const int bswz = col & 7;

    f32x4 acc1[4][4] = {};
    f32x4 acc3[4][4] = {};

    for (int k0 = 0; k0 < K; k0 += BK) {
        gll16(ga0 + k0, la0);
        gll16(ga1 + k0, la1);
#pragma unroll
        for (int j = 0; j < 4; j++) {
            gll16(g1 + (size_t)j * 8 * K + k0, lb1 + j * 8 * BK);
            gll16(g3 + (size_t)j * 8 * K + k0, lb3 + j * 8 * BK);
        }
        __syncthreads();

        short8 a[4];
#pragma unroll
        for (int mi = 0; mi < 4; mi++)
            a[mi] = *(const short8*)(As + (wr * 64 + mi * 16 + col) * BK + ((kg ^ aswz) * 8));
#pragma unroll
        for (int ni = 0; ni < 4; ni++) {
            const int rowB = wc * 64 + ni * 16 + col;
            const float* rb1 = B1f + rowB * BK;
            const float* rb3 = B3f + rowB * BK;
            const int c0 = ((kg * 2) ^ bswz) * 4;
            const int c1 = ((kg * 2 + 1) ^ bswz) * 4;
            short8 v1 = cvt8(*(const float4*)(rb1 + c0), *(const float4*)(rb1 + c1));
            short8 v3 = cvt8(*(const float4*)(rb3 + c0), *(const float4*)(rb3 + c1));
#pragma unroll
            for (int mi = 0; mi < 4; mi++) {
                acc1[mi][ni] = __builtin_amdgcn_mfma_f32_16x16x32_bf16(a[mi], v1, acc1[mi][ni], 0, 0, 0);
                acc3[mi][ni] = __builtin_amdgcn_mfma_f32_16x16x32_bf16(a[mi], v3, acc3[mi][ni], 0, 0, 0);
            }
        }
        __syncthreads();
    }

    // epilogue: h = silu(acc1) * acc3, store bf16 (padding rows produce 0)
#pragma unroll
    for (int mi = 0; mi < 4; mi++) {
#pragma unroll
        for (int j = 0; j < 4; j++) {
            int row = slot0 + wr * 64 + mi * 16 + kg * 4 + j;
#pragma unroll
            for (int ni = 0; ni < 4; ni++) {
                float v1 = acc1[mi][ni][j];
                float v3 = acc3[mi][ni][j];
                float hv = v1 / (1.f + __expf(-v1)) * v3;
                int c = n0 + wc * 64 + ni * 16 + col;
                H[(size_t)row * N + c] = f2bf(hv);
            }
        }
    }
}

template<bool ATOMIC>
__global__ __launch_bounds__(256, 2) void gemm_out_k(
    const u16* __restrict__ Hm,
    const float* __restrict__ W2b,
    float* __restrict__ Out,
    const int* __restrict__ perm, const float* __restrict__ pw,
    const int* __restrict__ te, const int* __restrict__ tr,
    int K, int nt_m, int chunk)
{
    const int q = (blockIdx.x & 7) * chunk + (blockIdx.x >> 3);
    if (q >= nt_m * (DIM_ / BN)) return;
    const int jn = q / nt_m, im = q % nt_m;
    int e, slot0;
    if (ATOMIC) { e = te[im]; if (e < 0) return; slot0 = tr[im]; }
    else        { e = 0; slot0 = im * BM; }
    const int n0 = jn * BN;
    const float* W2 = W2b + (size_t)e * DIM_ * K;

    __shared__ __align__(16) u16   As[BM * BK];
    __shared__ __align__(16) float Bf[BM * BK];

    const int tid = threadIdx.x;
    const int lane = tid & 63, wid = tid >> 6;
    const int wr = wid >> 1, wc = wid & 1;
    const int col = lane & 15, kg = lane >> 4;

    const int aRow = wid * 32 + (lane >> 2);
    const int aCk  = ((lane & 3) ^ ((lane >> 3) & 3)) * 8;
    const u16* ga0 = Hm + (size_t)(slot0 + aRow) * K + aCk;
    const u16* ga1 = Hm + (size_t)(slot0 + aRow + 16) * K + aCk;
    u16* la0 = As + (wid * 32) * BK;
    u16* la1 = As + (wid * 32 + 16) * BK;

    const int bRowL = lane >> 3;
    const int bCk   = ((lane & 7) ^ bRowL) * 4;
    const float* g2 = W2 + (size_t)(n0 + wid * 32 + bRowL) * K + bCk;
    float* lb = Bf + (wid * 32) * BK;

    const int aswz = (col >> 1) & 3;
    const int bswz = col & 7;

    f32x4 acc[4][4] = {};

    for (int k0 = 0; k0 < K; k0 += BK) {
        gll16(ga0 + k0, la0);
        gll16(ga1 + k0, la1);
#pragma unroll
        for (int j = 0; j < 4; j++)
            gll16(g2 + (size_t)j * 8 * K + k0, lb + j * 8 * BK);
        __syncthreads();

        short8 a[4];
#pragma unroll
        for (int mi = 0; mi < 4; mi++)
            a[mi] = *(const short8*)(As + (wr * 64 + mi * 16 + col) * BK + ((kg ^ aswz) * 8));
#pragma unroll
        for (int ni = 0; ni < 4; ni++) {
            const int rowB = wc * 64 + ni * 16 + col;
            const float* rb = Bf + rowB * BK;
            const int c0 = ((kg * 2) ^ bswz) * 4;
            const int c1 = ((kg * 2 + 1) ^ bswz) * 4;
            short8 bv = cvt8(*(const float4*)(rb + c0), *(const float4*)(rb + c1));
#pragma unroll
            for (int mi = 0; mi < 4; mi++)
                acc[mi][ni] = __builtin_amdgcn_mfma_f32_16x16x32_bf16(a[mi], bv, acc[mi][ni], 0, 0, 0);
        }
        __syncthreads();
    }

#pragma unroll
    for (int mi = 0; mi < 4; mi++) {
#pragma unroll
        for (int j = 0; j < 4; j++) {
            int rloc = wr * 64 + mi * 16 + kg * 4 + j;
            int slot = slot0 + rloc;
            if (ATOMIC) {
                int token = perm[slot];
                if (token < 0) continue;
                float w = pw[slot];
#pragma unroll
                for (int ni = 0; ni < 4; ni++) {
                    int c = n0 + wc * 64 + ni * 16 + col;
                    atomicAdd(&Out[(size_t)token * DIM_ + c], acc[mi][ni][j] * w);
                }
            } else {
#pragma unroll
                for (int ni = 0; ni < 4; ni++) {
                    int c = n0 + wc * 64 + ni * 16 + col;
                    Out[(size_t)slot * DIM_ + c] = acc[mi][ni][j];
                }
            }
        }
    }
}

// ---------------- launch ----------------

extern "C" void kernel_launch(void* const* d_in, const int* in_sizes, int n_in,
                              void* d_out, int out_size, void* d_ws, size_t ws_size,
                              hipStream_t stream) {
    (void)in_sizes; (void)n_in; (void)out_size; (void)ws_size;
    const float* x   = (const float*)d_in[0];
    const float* gw  = (const float*)d_in[1];
    const float* w1  = (const float*)d_in[2];
    const float* w2  = (const float*)d_in[3];
    const float* w3  = (const float*)d_in[4];
    const float* sw1 = (const float*)d_in[5];
    const float* sw2 = (const float*)d_in[6];
    const float* sw3 = (const float*)d_in[7];
    float* out = (float*)d_out;

    char* ws = (char*)d_ws;
    size_t off = 0;
    auto take = [&](size_t bytes) -> void* {
        void* p = ws + off;
        off += (bytes + 255) & ~(size_t)255;
        return p;
    };
    u16*   xb      = (u16*)take((size_t)TTOK * DIM_ * 2);
    u16*   hbuf    = (u16*)take((size_t)MAXROWS * INTER_ * 2);
    int*   perm_rt = (int*)take((size_t)MAXROWS * 4);
    float* pw_rt   = (float*)take((size_t)MAXROWS * 4);
    int*   perm_sh = (int*)take((size_t)TTOK * 4);
    int*   topi    = (int*)take((size_t)TTOK * 2 * 4);
    float* topw    = (float*)take((size_t)TTOK * 2 * 4);
    int*   misc    = (int*)take(1024);
    int*   zrow    = (int*)take(4096);

    init_kernel<<<MAXROWS / 256, 256, 0, stream>>>(perm_rt, pw_rt, perm_sh, misc, zrow);
    cvt_kernel<<<512, 256, 0, stream>>>(x, xb, TTOK * DIM_ / 8);
    gate_kernel<<<TTOK, 64, 0, stream>>>(x, gw, topi, topw, misc);
    scan_kernel<<<1, 1, 0, stream>>>(misc);
    scatter_kernel<<<TTOK / 256, 256, 0, stream>>>(topi, topw, misc, perm_rt, pw_rt);

    auto grid8 = [](int total) { return ((total + 7) / 8) * 8; };
    auto chunk8 = [](int total) { return (total + 7) / 8; };

    // shared expert
    {
        int total = (TTOK / BM) * (SINTER_ / BN);
        gemm_h13_k<false><<<grid8(total), 256, 0, stream>>>(
            xb, sw1, sw3, hbuf, perm_sh, nullptr, nullptr, (const u16*)zrow,
            SINTER_, DIM_, TTOK / BM, chunk8(total));
    }
    {
        int total = (TTOK / BM) * (DIM_ / BN);
        gemm_out_k<false><<<grid8(total), 256, 0, stream>>>(
            hbuf, sw2, out, nullptr, nullptr, nullptr, nullptr,
            SINTER_, TTOK / BM, chunk8(total));
    }
    // routed experts
    {
        int total = MAXMT * (INTER_ / BN);
        gemm_h13_k<true><<<grid8(total), 256, 0, stream>>>(
            xb, w1, w3, hbuf, perm_rt, misc + 48, misc + 128, (const u16*)zrow,
            INTER_, DIM_, MAXMT, chunk8(total));
    }
    {
        int total = MAXMT * (DIM_ / BN);
        gemm_out_k<true><<<grid8(total), 256, 0, stream>>>(
            hbuf, w2, out, perm_rt, pw_rt, misc + 48, misc + 128,
            INTER_, MAXMT, chunk8(total));
    }
}

// Round 7
// 876.452 us; speedup vs baseline: 3.2011x; 1.0029x over previous
//
#include <hip/hip_runtime.h>
#include <hip/hip_bf16.h>
#include <cstdint>
#include <cstddef>

#define TTOK   4096
#define DIM_   2048
#define INTER_ 1408
#define NEXP   16
#define SINTER_ 2816
#define BM 128
#define BN 128
#define BK 32
#define MAXROWS (TTOK*2 + NEXP*BM)      /* 10240 padded routed slots */
#define MAXMT   (TTOK*2/BM + NEXP)      /* 80 worst-case M tiles */

typedef unsigned short u16;
typedef __attribute__((ext_vector_type(8))) short short8;
typedef __attribute__((ext_vector_type(4))) float f32x4;

#define AS3P(p) ((__attribute__((address_space(3))) void*)(p))
#define AS1P(p) ((const __attribute__((address_space(1))) void*)(p))

__device__ __forceinline__ void gll16(const void* g, void* l) {
    __builtin_amdgcn_global_load_lds(AS1P(g), AS3P(l), 16, 0, 0);
}

__device__ __forceinline__ u16 f2bf(float f) {
    __hip_bfloat16 h = __float2bfloat16(f);
    union { __hip_bfloat16 h; u16 u; } c; c.h = h; return c.u;
}

__device__ __forceinline__ unsigned pk2(float a, float b) {
    unsigned r;
    asm("v_cvt_pk_bf16_f32 %0, %1, %2" : "=v"(r) : "v"(a), "v"(b));
    return r;
}

// two float4 (8 consecutive k-floats) -> short8 bf16 frag
__device__ __forceinline__ short8 cvt8(float4 q0, float4 q1) {
    union { int4 i; short8 s; } u;
    u.i = make_int4((int)pk2(q0.x, q0.y), (int)pk2(q0.z, q0.w),
                    (int)pk2(q1.x, q1.y), (int)pk2(q1.z, q1.w));
    return u.s;
}

__device__ __forceinline__ int4 pack8(float4 a, float4 b) {
    int4 r;
    r.x = (int)pk2(a.x, a.y);
    r.y = (int)pk2(a.z, a.w);
    r.z = (int)pk2(b.x, b.y);
    r.w = (int)pk2(b.z, b.w);
    return r;
}

// pipeline fences
#define WAIT_VM0_BARRIER() do { \
    asm volatile("s_waitcnt vmcnt(0)" ::: "memory"); \
    __builtin_amdgcn_s_barrier(); \
    asm volatile("" ::: "memory"); \
} while (0)

// ---------------- small kernels ----------------

// misc layout (ints): [0..16) counts, [16..32) fill, [32..48) base,
//                     [48..128) tile_expert, [128..208) tile_row0
__global__ void init_kernel(int* perm_rt, float* pw_rt, int* perm_sh, int* misc, int* zrow) {
    int i = blockIdx.x * 256 + threadIdx.x;
    if (i < MAXROWS) { perm_rt[i] = -1; pw_rt[i] = 0.f; }
    if (i < TTOK)    perm_sh[i] = i;
    if (i < 32)      misc[i] = 0;
    if (i < 1024)    zrow[i] = 0;      // 4 KB zero page
}

// f32 -> bf16, 8 elems/thread, grid-stride (used for x only)
__global__ void cvt_kernel(const float* __restrict__ s, u16* __restrict__ d, int n8) {
    int stride = gridDim.x * 256;
    for (int i = blockIdx.x * 256 + threadIdx.x; i < n8; i += stride) {
        const float4* s4 = (const float4*)(s + (size_t)i * 8);
        float4 a = s4[0], b = s4[1];
        *(int4*)(d + (size_t)i * 8) = pack8(a, b);
    }
}

__global__ void gate_kernel(const float* __restrict__ x, const float* __restrict__ gw,
                            int* __restrict__ topi, float* __restrict__ topw,
                            int* __restrict__ misc) {
    int t = blockIdx.x;
    int lane = threadIdx.x;
    const float* xr = x + (size_t)t * DIM_;
    float acc[NEXP];
#pragma unroll
    for (int e = 0; e < NEXP; e++) acc[e] = 0.f;
#pragma unroll
    for (int i = 0; i < 8; i++) {
        int k = i * 256 + lane * 4;
        float4 xv = *(const float4*)(xr + k);
#pragma unroll
        for (int e = 0; e < NEXP; e++) {
            float4 gv = *(const float4*)(gw + (size_t)e * DIM_ + k);
            acc[e] += xv.x * gv.x + xv.y * gv.y + xv.z * gv.z + xv.w * gv.w;
        }
    }
#pragma unroll
    for (int e = 0; e < NEXP; e++) {
        float v = acc[e];
        for (int off = 32; off > 0; off >>= 1) v += __shfl_down(v, off);
        acc[e] = v;
    }
    if (lane == 0) {
        float m = acc[0];
#pragma unroll
        for (int e = 1; e < NEXP; e++) m = fmaxf(m, acc[e]);
        float p[NEXP]; float s = 0.f;
#pragma unroll
        for (int e = 0; e < NEXP; e++) { p[e] = __expf(acc[e] - m); s += p[e]; }
        int i0 = 0; float v0 = p[0];
#pragma unroll
        for (int e = 1; e < NEXP; e++) if (p[e] > v0) { v0 = p[e]; i0 = e; }
        int i1 = -1; float v1 = -1.f;
#pragma unroll
        for (int e = 0; e < NEXP; e++) if (e != i0 && p[e] > v1) { v1 = p[e]; i1 = e; }
        float inv = 1.f / s;
        topi[2 * t] = i0; topi[2 * t + 1] = i1;
        topw[2 * t] = v0 * inv; topw[2 * t + 1] = v1 * inv;
        atomicAdd(&misc[i0], 1);
        atomicAdd(&misc[i1], 1);
    }
}

__global__ void scan_kernel(int* misc) {
    int* counts = misc;
    int* base   = misc + 32;
    int* te     = misc + 48;
    int* tr     = misc + 128;
    int b = 0, tt = 0;
    for (int e = 0; e < NEXP; e++) {
        int c = counts[e];
        int nt = (c + BM - 1) >> 7;
        base[e] = b;
        for (int i = 0; i < nt; i++) { te[tt] = e; tr[tt] = b + i * BM; tt++; }
        b += nt * BM;
    }
    for (int i = tt; i < MAXMT; i++) te[i] = -1;
}

__global__ void scatter_kernel(const int* __restrict__ topi, const float* __restrict__ topw,
                               int* __restrict__ misc, int* __restrict__ perm,
                               float* __restrict__ pw) {
    int t = blockIdx.x * 256 + threadIdx.x;
    if (t >= TTOK) return;
    int* fill = misc + 16;
    int* base = misc + 32;
#pragma unroll
    for (int k = 0; k < 2; k++) {
        int e = topi[2 * t + k];
        int pos = base[e] + atomicAdd(&fill[e], 1);
        perm[pos] = t;
        pw[pos] = topw[2 * t + k];
    }
}

// ---------------- GEMM kernels ----------------
// C[M,N] = A[M,K] @ B[N,K]^T ; A bf16 in LDS, B f32 in LDS (gll16-staged,
// converted to bf16 on fragment read via v_cvt_pk_bf16_f32). No weight cvt pass.
// DOUBLE-BUFFERED pipeline (T3 minimum-2-phase): per K-step
//   STAGE(t+1 -> buf^1) ; compute(t from buf) ; s_waitcnt vmcnt(0) ; s_barrier
// so next-tile loads are in flight during the whole compute phase (no
// __syncthreads in the loop: its implicit vmcnt(0) right after issue was the
// R6 stall — full load latency every K-step).
// XOR swizzles (both-sides: pre-swizzled per-lane GLOBAL src + swizzled read):
//   A bf16 [128][32]: src chunk (l&3)^((l>>3)&3); read chunk kg^((col>>1)&3)
//   B f32  [128][32f]: src chunk (l&7)^(l>>3);    read chunk c^(col&7)
// XCD-chunked jn-major 1D grid (T1).
// NOTE: __launch_bounds__(256,2) REQUIRED — (256,4) spills acc (R5: 8x slowdown).

template<bool GROUPED>
__global__ __launch_bounds__(256, 2) void gemm_h13_k(
    const u16* __restrict__ Xb,
    const float* __restrict__ W1b, const float* __restrict__ W3b,
    u16* __restrict__ H,
    const int* __restrict__ perm,
    const int* __restrict__ te, const int* __restrict__ tr,
    const u16* __restrict__ zrow,
    int N, int K, int nt_m, int chunk)
{
    const int q = (blockIdx.x & 7) * chunk + (blockIdx.x >> 3);
    if (q >= nt_m * (N / BN)) return;
    const int jn = q / nt_m, im = q % nt_m;
    int e, slot0;
    if (GROUPED) { e = te[im]; if (e < 0) return; slot0 = tr[im]; }
    else         { e = 0; slot0 = im * BM; }
    const int n0 = jn * BN;
    const float* W1 = W1b + (size_t)e * N * K;
    const float* W3 = W3b + (size_t)e * N * K;

    __shared__ __align__(16) u16   As[2][BM * BK];
    __shared__ __align__(16) float B1f[2][BM * BK];
    __shared__ __align__(16) float B3f[2][BM * BK];

    const int tid = threadIdx.x;
    const int lane = tid & 63, wid = tid >> 6;
    const int wr = wid >> 1, wc = wid & 1;
    const int col = lane & 15, kg = lane >> 4;

    // ---- A staging: 2 insts/wave, 16 rows each; lane -> row base+(l>>2), swz chunk
    const int aRow = wid * 32 + (lane >> 2);
    const int aCk  = ((lane & 3) ^ ((lane >> 3) & 3)) * 8;   // u16 elems
    const int ta0 = perm[slot0 + aRow];
    const int ta1 = perm[slot0 + aRow + 16];
    const u16* ga0 = (ta0 >= 0 ? Xb + (size_t)ta0 * K : zrow) + aCk;
    const u16* ga1 = (ta1 >= 0 ? Xb + (size_t)ta1 * K : zrow) + aCk;
    const int laOff0 = (wid * 32) * BK;
    const int laOff1 = (wid * 32 + 16) * BK;

    // ---- B staging: 4 insts/wave each matrix, 8 rows per inst
    const int bRowL = lane >> 3;                       // row within inst group
    const int bCk   = ((lane & 7) ^ bRowL) * 4;        // float offset in row
    const float* g1 = W1 + (size_t)(n0 + wid * 32 + bRowL) * K + bCk;
    const float* g3 = W3 + (size_t)(n0 + wid * 32 + bRowL) * K + bCk;
    const int lbOff = (wid * 32) * BK;

    // ---- fragment read constants
    const int aswz = (col >> 1) & 3;
    const int bswz = col & 7;

    f32x4 acc1[4][4] = {};
    f32x4 acc3[4][4] = {};

    // prologue: stage tile 0 into buf 0
    {
        gll16(ga0, &As[0][laOff0]);
        gll16(ga1, &As[0][laOff1]);
#pragma unroll
        for (int j = 0; j < 4; j++) {
            gll16(g1 + (size_t)j * 8 * K, &B1f[0][lbOff + j * 8 * BK]);
            gll16(g3 + (size_t)j * 8 * K, &B3f[0][lbOff + j * 8 * BK]);
        }
    }
    WAIT_VM0_BARRIER();

    int cur = 0;
    for (int k0 = 0; k0 < K; k0 += BK) {
        const int kn = k0 + BK;
        if (kn < K) {
            const int nb = cur ^ 1;
            gll16(ga0 + kn, &As[nb][laOff0]);
            gll16(ga1 + kn, &As[nb][laOff1]);
#pragma unroll
            for (int j = 0; j < 4; j++) {
                gll16(g1 + (size_t)j * 8 * K + kn, &B1f[nb][lbOff + j * 8 * BK]);
                gll16(g3 + (size_t)j * 8 * K + kn, &B3f[nb][lbOff + j * 8 * BK]);
            }
        }

        const u16*   Ac  = As[cur];
        const float* B1c = B1f[cur];
        const float* B3c = B3f[cur];

        short8 a[4];
#pragma unroll
        for (int mi = 0; mi < 4; mi++)
            a[mi] = *(const short8*)(Ac + (wr * 64 + mi * 16 + col) * BK + ((kg ^ aswz) * 8));
#pragma unroll
        for (int ni = 0; ni < 4; ni++) {
            const int rowB = wc * 64 + ni * 16 + col;
            const float* rb1 = B1c + rowB * BK;
            const float* rb3 = B3c + rowB * BK;
            const int c0 = ((kg * 2) ^ bswz) * 4;
            const int c1 = ((kg * 2 + 1) ^ bswz) * 4;
            short8 v1 = cvt8(*(const float4*)(rb1 + c0), *(const float4*)(rb1 + c1));
            short8 v3 = cvt8(*(const float4*)(rb3 + c0), *(const float4*)(rb3 + c1));
#pragma unroll
            for (int mi = 0; mi < 4; mi++) {
                acc1[mi][ni] = __builtin_amdgcn_mfma_f32_16x16x32_bf16(a[mi], v1, acc1[mi][ni], 0, 0, 0);
                acc3[mi][ni] = __builtin_amdgcn_mfma_f32_16x16x32_bf16(a[mi], v3, acc3[mi][ni], 0, 0, 0);
            }
        }

        WAIT_VM0_BARRIER();
        cur ^= 1;
    }

    // epilogue: h = silu(acc1) * acc3, store bf16 (padding rows produce 0)
#pragma unroll
    for (int mi = 0; mi < 4; mi++) {
#pragma unroll
        for (int j = 0; j < 4; j++) {
            int row = slot0 + wr * 64 + mi * 16 + kg * 4 + j;
#pragma unroll
            for (int ni = 0; ni < 4; ni++) {
                float v1 = acc1[mi][ni][j];
                float v3 = acc3[mi][ni][j];
                float hv = v1 / (1.f + __expf(-v1)) * v3;
                int c = n0 + wc * 64 + ni * 16 + col;
                H[(size_t)row * N + c] = f2bf(hv);
            }
        }
    }
}

template<bool ATOMIC>
__global__ __launch_bounds__(256, 2) void gemm_out_k(
    const u16* __restrict__ Hm,
    const float* __restrict__ W2b,
    float* __restrict__ Out,
    const int* __restrict__ perm, const float* __restrict__ pw,
    const int* __restrict__ te, const int* __restrict__ tr,
    int K, int nt_m, int chunk)
{
    const int q = (blockIdx.x & 7) * chunk + (blockIdx.x >> 3);
    if (q >= nt_m * (DIM_ / BN)) return;
    const int jn = q / nt_m, im = q % nt_m;
    int e, slot0;
    if (ATOMIC) { e = te[im]; if (e < 0) return; slot0 = tr[im]; }
    else        { e = 0; slot0 = im * BM; }
    const int n0 = jn * BN;
    const float* W2 = W2b + (size_t)e * DIM_ * K;

    __shared__ __align__(16) u16   As[2][BM * BK];
    __shared__ __align__(16) float Bf[2][BM * BK];

    const int tid = threadIdx.x;
    const int lane = tid & 63, wid = tid >> 6;
    const int wr = wid >> 1, wc = wid & 1;
    const int col = lane & 15, kg = lane >> 4;

    const int aRow = wid * 32 + (lane >> 2);
    const int aCk  = ((lane & 3) ^ ((lane >> 3) & 3)) * 8;
    const u16* ga0 = Hm + (size_t)(slot0 + aRow) * K + aCk;
    const u16* ga1 = Hm + (size_t)(slot0 + aRow + 16) * K + aCk;
    const int laOff0 = (wid * 32) * BK;
    const int laOff1 = (wid * 32 + 16) * BK;

    const int bRowL = lane >> 3;
    const int bCk   = ((lane & 7) ^ bRowL) * 4;
    const float* g2 = W2 + (size_t)(n0 + wid * 32 + bRowL) * K + bCk;
    const int lbOff = (wid * 32) * BK;

    const int aswz = (col >> 1) & 3;
    const int bswz = col & 7;

    f32x4 acc[4][4] = {};

    {
        gll16(ga0, &As[0][laOff0]);
        gll16(ga1, &As[0][laOff1]);
#pragma unroll
        for (int j = 0; j < 4; j++)
            gll16(g2 + (size_t)j * 8 * K, &Bf[0][lbOff + j * 8 * BK]);
    }
    WAIT_VM0_BARRIER();

    int cur = 0;
    for (int k0 = 0; k0 < K; k0 += BK) {
        const int kn = k0 + BK;
        if (kn < K) {
            const int nb = cur ^ 1;
            gll16(ga0 + kn, &As[nb][laOff0]);
            gll16(ga1 + kn, &As[nb][laOff1]);
#pragma unroll
            for (int j = 0; j < 4; j++)
                gll16(g2 + (size_t)j * 8 * K + kn, &Bf[nb][lbOff + j * 8 * BK]);
        }

        const u16*   Ac = As[cur];
        const float* Bc = Bf[cur];

        short8 a[4];
#pragma unroll
        for (int mi = 0; mi < 4; mi++)
            a[mi] = *(const short8*)(Ac + (wr * 64 + mi * 16 + col) * BK + ((kg ^ aswz) * 8));
#pragma unroll
        for (int ni = 0; ni < 4; ni++) {
            const int rowB = wc * 64 + ni * 16 + col;
            const float* rb = Bc + rowB * BK;
            const int c0 = ((kg * 2) ^ bswz) * 4;
            const int c1 = ((kg * 2 + 1) ^ bswz) * 4;
            short8 bv = cvt8(*(const float4*)(rb + c0), *(const float4*)(rb + c1));
#pragma unroll
            for (int mi = 0; mi < 4; mi++)
                acc[mi][ni] = __builtin_amdgcn_mfma_f32_16x16x32_bf16(a[mi], bv, acc[mi][ni], 0, 0, 0);
        }

        WAIT_VM0_BARRIER();
        cur ^= 1;
    }

#pragma unroll
    for (int mi = 0; mi < 4; mi++) {
#pragma unroll
        for (int j = 0; j < 4; j++) {
            int rloc = wr * 64 + mi * 16 + kg * 4 + j;
            int slot = slot0 + rloc;
            if (ATOMIC) {
                int token = perm[slot];
                if (token < 0) continue;
                float w = pw[slot];
#pragma unroll
                for (int ni = 0; ni < 4; ni++) {
                    int c = n0 + wc * 64 + ni * 16 + col;
                    atomicAdd(&Out[(size_t)token * DIM_ + c], acc[mi][ni][j] * w);
                }
            } else {
#pragma unroll
                for (int ni = 0; ni < 4; ni++) {
                    int c = n0 + wc * 64 + ni * 16 + col;
                    Out[(size_t)slot * DIM_ + c] = acc[mi][ni][j];
                }
            }
        }
    }
}

// ---------------- launch ----------------

extern "C" void kernel_launch(void* const* d_in, const int* in_sizes, int n_in,
                              void* d_out, int out_size, void* d_ws, size_t ws_size,
                              hipStream_t stream) {
    (void)in_sizes; (void)n_in; (void)out_size; (void)ws_size;
    const float* x   = (const float*)d_in[0];
    const float* gw  = (const float*)d_in[1];
    const float* w1  = (const float*)d_in[2];
    const float* w2  = (const float*)d_in[3];
    const float* w3  = (const float*)d_in[4];
    const float* sw1 = (const float*)d_in[5];
    const float* sw2 = (const float*)d_in[6];
    const float* sw3 = (const float*)d_in[7];
    float* out = (float*)d_out;

    char* ws = (char*)d_ws;
    size_t off = 0;
    auto take = [&](size_t bytes) -> void* {
        void* p = ws + off;
        off += (bytes + 255) & ~(size_t)255;
        return p;
    };
    u16*   xb      = (u16*)take((size_t)TTOK * DIM_ * 2);
    u16*   hbuf    = (u16*)take((size_t)MAXROWS * INTER_ * 2);
    int*   perm_rt = (int*)take((size_t)MAXROWS * 4);
    float* pw_rt   = (float*)take((size_t)MAXROWS * 4);
    int*   perm_sh = (int*)take((size_t)TTOK * 4);
    int*   topi    = (int*)take((size_t)TTOK * 2 * 4);
    float* topw    = (float*)take((size_t)TTOK * 2 * 4);
    int*   misc    = (int*)take(1024);
    int*   zrow    = (int*)take(4096);

    init_kernel<<<MAXROWS / 256, 256, 0, stream>>>(perm_rt, pw_rt, perm_sh, misc, zrow);
    cvt_kernel<<<512, 256, 0, stream>>>(x, xb, TTOK * DIM_ / 8);
    gate_kernel<<<TTOK, 64, 0, stream>>>(x, gw, topi, topw, misc);
    scan_kernel<<<1, 1, 0, stream>>>(misc);
    scatter_kernel<<<TTOK / 256, 256, 0, stream>>>(topi, topw, misc, perm_rt, pw_rt);

    auto grid8 = [](int total) { return ((total + 7) / 8) * 8; };
    auto chunk8 = [](int total) { return (total + 7) / 8; };

    // shared expert
    {
        int total = (TTOK / BM) * (SINTER_ / BN);
        gemm_h13_k<false><<<grid8(total), 256, 0, stream>>>(
            xb, sw1, sw3, hbuf, perm_sh, nullptr, nullptr, (const u16*)zrow,
            SINTER_, DIM_, TTOK / BM, chunk8(total));
    }
    {
        int total = (TTOK / BM) * (DIM_ / BN);
        gemm_out_k<false><<<grid8(total), 256, 0, stream>>>(
            hbuf, sw2, out, nullptr, nullptr, nullptr, nullptr,
            SINTER_, TTOK / BM, chunk8(total));
    }
    // routed experts
    {
        int total = MAXMT * (INTER_ / BN);
        gemm_h13_k<true><<<grid8(total), 256, 0, stream>>>(
            xb, w1, w3, hbuf, perm_rt, misc + 48, misc + 128, (const u16*)zrow,
            INTER_, DIM_, MAXMT, chunk8(total));
    }
    {
        int total = MAXMT * (DIM_ / BN);
        gemm_out_k<true><<<grid8(total), 256, 0, stream>>>(
            hbuf, w2, out, perm_rt, pw_rt, misc + 48, misc + 128,
            INTER_, MAXMT, chunk8(total));
    }
}

// Round 8
// 864.049 us; speedup vs baseline: 3.2470x; 1.0144x over previous
//
#include <hip/hip_runtime.h>
#include <hip/hip_bf16.h>
#include <cstdint>
#include <cstddef>

#define TTOK   4096
#define DIM_   2048
#define INTER_ 1408
#define NEXP   16
#define SINTER_ 2816
#define BM 128
#define BN 128
#define BK 32
#define MAXROWS (TTOK*2 + NEXP*BM)      /* 10240 padded routed slots */
#define MAXMT   (TTOK*2/BM + NEXP)      /* 80 worst-case M tiles */

typedef unsigned short u16;
typedef __attribute__((ext_vector_type(8))) short short8;
typedef __attribute__((ext_vector_type(4))) float f32x4;

#define AS3P(p) ((__attribute__((address_space(3))) void*)(p))
#define AS1P(p) ((const __attribute__((address_space(1))) void*)(p))

__device__ __forceinline__ void gll16(const void* g, void* l) {
    __builtin_amdgcn_global_load_lds(AS1P(g), AS3P(l), 16, 0, 0);
}

__device__ __forceinline__ u16 f2bf(float f) {
    __hip_bfloat16 h = __float2bfloat16(f);
    union { __hip_bfloat16 h; u16 u; } c; c.h = h; return c.u;
}

__device__ __forceinline__ unsigned pk2(float a, float b) {
    unsigned r;
    asm("v_cvt_pk_bf16_f32 %0, %1, %2" : "=v"(r) : "v"(a), "v"(b));
    return r;
}

__device__ __forceinline__ int4 pack8(float4 a, float4 b) {
    int4 r;
    r.x = (int)pk2(a.x, a.y);
    r.y = (int)pk2(a.z, a.w);
    r.z = (int)pk2(b.x, b.y);
    r.w = (int)pk2(b.z, b.w);
    return r;
}

// ---------------- small kernels ----------------

// misc layout (ints): [0..16) counts, [16..32) fill, [32..48) base,
//                     [48..128) tile_expert, [128..208) tile_row0
__global__ void init_kernel(int* perm_rt, float* pw_rt, int* perm_sh, int* misc, int* zrow) {
    int i = blockIdx.x * 256 + threadIdx.x;
    if (i < MAXROWS) { perm_rt[i] = -1; pw_rt[i] = 0.f; }
    if (i < TTOK)    perm_sh[i] = i;
    if (i < 32)      misc[i] = 0;
    if (i < 1024)    zrow[i] = 0;      // 4 KB zero page
}

// f32 -> bf16, 8 elems/thread, grid-stride
__global__ void cvt_kernel(const float* __restrict__ s, u16* __restrict__ d, int n8) {
    int stride = gridDim.x * 256;
    for (int i = blockIdx.x * 256 + threadIdx.x; i < n8; i += stride) {
        const float4* s4 = (const float4*)(s + (size_t)i * 8);
        float4 a = s4[0], b = s4[1];
        *(int4*)(d + (size_t)i * 8) = pack8(a, b);
    }
}

__global__ void gate_kernel(const float* __restrict__ x, const float* __restrict__ gw,
                            int* __restrict__ topi, float* __restrict__ topw,
                            int* __restrict__ misc) {
    int t = blockIdx.x;
    int lane = threadIdx.x;
    const float* xr = x + (size_t)t * DIM_;
    float acc[NEXP];
#pragma unroll
    for (int e = 0; e < NEXP; e++) acc[e] = 0.f;
#pragma unroll
    for (int i = 0; i < 8; i++) {
        int k = i * 256 + lane * 4;
        float4 xv = *(const float4*)(xr + k);
#pragma unroll
        for (int e = 0; e < NEXP; e++) {
            float4 gv = *(const float4*)(gw + (size_t)e * DIM_ + k);
            acc[e] += xv.x * gv.x + xv.y * gv.y + xv.z * gv.z + xv.w * gv.w;
        }
    }
#pragma unroll
    for (int e = 0; e < NEXP; e++) {
        float v = acc[e];
        for (int off = 32; off > 0; off >>= 1) v += __shfl_down(v, off);
        acc[e] = v;
    }
    if (lane == 0) {
        float m = acc[0];
#pragma unroll
        for (int e = 1; e < NEXP; e++) m = fmaxf(m, acc[e]);
        float p[NEXP]; float s = 0.f;
#pragma unroll
        for (int e = 0; e < NEXP; e++) { p[e] = __expf(acc[e] - m); s += p[e]; }
        int i0 = 0; float v0 = p[0];
#pragma unroll
        for (int e = 1; e < NEXP; e++) if (p[e] > v0) { v0 = p[e]; i0 = e; }
        int i1 = -1; float v1 = -1.f;
#pragma unroll
        for (int e = 0; e < NEXP; e++) if (e != i0 && p[e] > v1) { v1 = p[e]; i1 = e; }
        float inv = 1.f / s;
        topi[2 * t] = i0; topi[2 * t + 1] = i1;
        topw[2 * t] = v0 * inv; topw[2 * t + 1] = v1 * inv;
        atomicAdd(&misc[i0], 1);
        atomicAdd(&misc[i1], 1);
    }
}

__global__ void scan_kernel(int* misc) {
    int* counts = misc;
    int* base   = misc + 32;
    int* te     = misc + 48;
    int* tr     = misc + 128;
    int b = 0, tt = 0;
    for (int e = 0; e < NEXP; e++) {
        int c = counts[e];
        int nt = (c + BM - 1) >> 7;
        base[e] = b;
        for (int i = 0; i < nt; i++) { te[tt] = e; tr[tt] = b + i * BM; tt++; }
        b += nt * BM;
    }
    for (int i = tt; i < MAXMT; i++) te[i] = -1;
}

__global__ void scatter_kernel(const int* __restrict__ topi, const float* __restrict__ topw,
                               int* __restrict__ misc, int* __restrict__ perm,
                               float* __restrict__ pw) {
    int t = blockIdx.x * 256 + threadIdx.x;
    if (t >= TTOK) return;
    int* fill = misc + 16;
    int* base = misc + 32;
#pragma unroll
    for (int k = 0; k < 2; k++) {
        int e = topi[2 * t + k];
        int pos = base[e] + atomicAdd(&fill[e], 1);
        perm[pos] = t;
        pw[pos] = topw[2 * t + k];
    }
}

// ---------------- GEMM kernels (all-bf16, gll16 staging, R4 skeleton) ----------------
// C[M,N] = A[M,K] @ B[N,K]^T ; A,B bf16 in LDS via global_load_lds dwordx4.
// Plain sync loop (fastest measured at 128^2: R4=175us; dbuf/f32 variants 237-245).
// XOR swizzle scheme-B on BOTH A and B (R5/R7-verified involution):
//   store: lane l (row r=l>>2, chunk c=l&3) pre-swizzles GLOBAL chunk c^((l>>3)&3)
//          (= c ^ ((r>>1)&3)); gll16 dest stays linear (HW: base + lane*16B).
//   read : frag at row ..+col reads chunk kg^((col>>1)&3).
//   banks: 8-way -> 2-way (free, m136).
// XCD-chunked jn-major 1D grid (T1).
// NOTE: __launch_bounds__(256,2) REQUIRED — (256,4) spills acc (R5: 8x slowdown).

template<bool GROUPED>
__global__ __launch_bounds__(256, 2) void gemm_h13_k(
    const u16* __restrict__ Xb,
    const u16* __restrict__ W1b, const u16* __restrict__ W3b,
    u16* __restrict__ H,
    const int* __restrict__ perm,
    const int* __restrict__ te, const int* __restrict__ tr,
    const u16* __restrict__ zrow,
    int N, int K, int nt_m, int chunk)
{
    const int q = (blockIdx.x & 7) * chunk + (blockIdx.x >> 3);
    if (q >= nt_m * (N / BN)) return;
    const int jn = q / nt_m, im = q % nt_m;
    int e, slot0;
    if (GROUPED) { e = te[im]; if (e < 0) return; slot0 = tr[im]; }
    else         { e = 0; slot0 = im * BM; }
    const int n0 = jn * BN;
    const u16* W1 = W1b + (size_t)e * N * K;
    const u16* W3 = W3b + (size_t)e * N * K;

    __shared__ __align__(16) u16 As[BM * BK];
    __shared__ __align__(16) u16 B1s[BM * BK];
    __shared__ __align__(16) u16 B3s[BM * BK];

    const int tid = threadIdx.x;
    const int lane = tid & 63, wid = tid >> 6;
    const int wr = wid >> 1, wc = wid & 1;
    const int col = lane & 15, kg = lane >> 4;

    // staging: per wave 2 insts/matrix-tile-half, 16 rows each.
    // lane l -> row l>>2, pre-swizzled global chunk (l&3)^((l>>3)&3), 16 B.
    const int lr = lane >> 2;
    const int kb = ((lane & 3) ^ ((lane >> 3) & 3)) * 8;   // u16 elems
    const int ar0 = wid * 32 + lr, ar1 = ar0 + 16;
    const int ta0 = perm[slot0 + ar0];
    const int ta1 = perm[slot0 + ar1];
    const u16* ga0 = (ta0 >= 0 ? Xb + (size_t)ta0 * K : zrow) + kb;
    const u16* ga1 = (ta1 >= 0 ? Xb + (size_t)ta1 * K : zrow) + kb;
    const u16* gb1a = W1 + (size_t)(n0 + ar0) * K + kb;
    const u16* gb1b = W1 + (size_t)(n0 + ar1) * K + kb;
    const u16* gb3a = W3 + (size_t)(n0 + ar0) * K + kb;
    const u16* gb3b = W3 + (size_t)(n0 + ar1) * K + kb;
    u16* la0 = As  + (wid * 32) * BK;        // wave-uniform; HW adds lane*16B
    u16* la1 = As  + (wid * 32 + 16) * BK;
    u16* lb1a = B1s + (wid * 32) * BK;
    u16* lb1b = B1s + (wid * 32 + 16) * BK;
    u16* lb3a = B3s + (wid * 32) * BK;
    u16* lb3b = B3s + (wid * 32 + 16) * BK;

    const int sw = (col >> 1) & 3;           // read-side swizzle key

    f32x4 acc1[4][4] = {};
    f32x4 acc3[4][4] = {};

    for (int k0 = 0; k0 < K; k0 += BK) {
        gll16(ga0 + k0, la0);
        gll16(ga1 + k0, la1);
        gll16(gb1a + k0, lb1a);
        gll16(gb1b + k0, lb1b);
        gll16(gb3a + k0, lb3a);
        gll16(gb3b + k0, lb3b);
        __syncthreads();

        short8 a[4];
#pragma unroll
        for (int mi = 0; mi < 4; mi++)
            a[mi] = *(const short8*)(As + (wr * 64 + mi * 16 + col) * BK + ((kg ^ sw) * 8));
#pragma unroll
        for (int ni = 0; ni < 4; ni++) {
            const int rowB = (wc * 64 + ni * 16 + col) * BK + ((kg ^ sw) * 8);
            short8 v1 = *(const short8*)(B1s + rowB);
            short8 v3 = *(const short8*)(B3s + rowB);
#pragma unroll
            for (int mi = 0; mi < 4; mi++) {
                acc1[mi][ni] = __builtin_amdgcn_mfma_f32_16x16x32_bf16(a[mi], v1, acc1[mi][ni], 0, 0, 0);
                acc3[mi][ni] = __builtin_amdgcn_mfma_f32_16x16x32_bf16(a[mi], v3, acc3[mi][ni], 0, 0, 0);
            }
        }
        __syncthreads();
    }

    // epilogue: h = silu(acc1) * acc3, store bf16 (padding rows produce 0)
#pragma unroll
    for (int mi = 0; mi < 4; mi++) {
#pragma unroll
        for (int j = 0; j < 4; j++) {
            int row = slot0 + wr * 64 + mi * 16 + kg * 4 + j;
#pragma unroll
            for (int ni = 0; ni < 4; ni++) {
                float v1 = acc1[mi][ni][j];
                float v3 = acc3[mi][ni][j];
                float hv = v1 / (1.f + __expf(-v1)) * v3;
                int c = n0 + wc * 64 + ni * 16 + col;
                H[(size_t)row * N + c] = f2bf(hv);
            }
        }
    }
}

template<bool ATOMIC>
__global__ __launch_bounds__(256, 2) void gemm_out_k(
    const u16* __restrict__ Hm,
    const u16* __restrict__ W2b,
    float* __restrict__ Out,
    const int* __restrict__ perm, const float* __restrict__ pw,
    const int* __restrict__ te, const int* __restrict__ tr,
    int K, int nt_m, int chunk)
{
    const int q = (blockIdx.x & 7) * chunk + (blockIdx.x >> 3);
    if (q >= nt_m * (DIM_ / BN)) return;
    const int jn = q / nt_m, im = q % nt_m;
    int e, slot0;
    if (ATOMIC) { e = te[im]; if (e < 0) return; slot0 = tr[im]; }
    else        { e = 0; slot0 = im * BM; }
    const int n0 = jn * BN;
    const u16* W2 = W2b + (size_t)e * DIM_ * K;

    __shared__ __align__(16) u16 As[BM * BK];
    __shared__ __align__(16) u16 Bs[BM * BK];

    const int tid = threadIdx.x;
    const int lane = tid & 63, wid = tid >> 6;
    const int wr = wid >> 1, wc = wid & 1;
    const int col = lane & 15, kg = lane >> 4;

    const int lr = lane >> 2;
    const int kb = ((lane & 3) ^ ((lane >> 3) & 3)) * 8;
    const int ar0 = wid * 32 + lr, ar1 = ar0 + 16;
    const u16* ga0 = Hm + (size_t)(slot0 + ar0) * K + kb;
    const u16* ga1 = Hm + (size_t)(slot0 + ar1) * K + kb;
    const u16* gb0 = W2 + (size_t)(n0 + ar0) * K + kb;
    const u16* gb1 = W2 + (size_t)(n0 + ar1) * K + kb;
    u16* la0 = As + (wid * 32) * BK;
    u16* la1 = As + (wid * 32 + 16) * BK;
    u16* lb0 = Bs + (wid * 32) * BK;
    u16* lb1 = Bs + (wid * 32 + 16) * BK;

    const int sw = (col >> 1) & 3;

    f32x4 acc[4][4] = {};

    for (int k0 = 0; k0 < K; k0 += BK) {
        gll16(ga0 + k0, la0);
        gll16(ga1 + k0, la1);
        gll16(gb0 + k0, lb0);
        gll16(gb1 + k0, lb1);
        __syncthreads();

        short8 a[4];
#pragma unroll
        for (int mi = 0; mi < 4; mi++)
            a[mi] = *(const short8*)(As + (wr * 64 + mi * 16 + col) * BK + ((kg ^ sw) * 8));
#pragma unroll
        for (int ni = 0; ni < 4; ni++) {
            short8 bv = *(const short8*)(Bs + (wc * 64 + ni * 16 + col) * BK + ((kg ^ sw) * 8));
#pragma unroll
            for (int mi = 0; mi < 4; mi++)
                acc[mi][ni] = __builtin_amdgcn_mfma_f32_16x16x32_bf16(a[mi], bv, acc[mi][ni], 0, 0, 0);
        }
        __syncthreads();
    }

#pragma unroll
    for (int mi = 0; mi < 4; mi++) {
#pragma unroll
        for (int j = 0; j < 4; j++) {
            int rloc = wr * 64 + mi * 16 + kg * 4 + j;
            int slot = slot0 + rloc;
            if (ATOMIC) {
                int token = perm[slot];
                if (token < 0) continue;
                float w = pw[slot];
#pragma unroll
                for (int ni = 0; ni < 4; ni++) {
                    int c = n0 + wc * 64 + ni * 16 + col;
                    atomicAdd(&Out[(size_t)token * DIM_ + c], acc[mi][ni][j] * w);
                }
            } else {
#pragma unroll
                for (int ni = 0; ni < 4; ni++) {
                    int c = n0 + wc * 64 + ni * 16 + col;
                    Out[(size_t)slot * DIM_ + c] = acc[mi][ni][j];
                }
            }
        }
    }
}

// ---------------- launch ----------------

extern "C" void kernel_launch(void* const* d_in, const int* in_sizes, int n_in,
                              void* d_out, int out_size, void* d_ws, size_t ws_size,
                              hipStream_t stream) {
    (void)in_sizes; (void)n_in; (void)out_size; (void)ws_size;
    const float* x   = (const float*)d_in[0];
    const float* gw  = (const float*)d_in[1];
    const float* w1  = (const float*)d_in[2];
    const float* w2  = (const float*)d_in[3];
    const float* w3  = (const float*)d_in[4];
    const float* sw1 = (const float*)d_in[5];
    const float* sw2 = (const float*)d_in[6];
    const float* sw3 = (const float*)d_in[7];
    float* out = (float*)d_out;

    char* ws = (char*)d_ws;
    size_t off = 0;
    auto take = [&](size_t bytes) -> void* {
        void* p = ws + off;
        off += (bytes + 255) & ~(size_t)255;
        return p;
    };
    u16*   xb      = (u16*)take((size_t)TTOK * DIM_ * 2);
    u16*   hbuf    = (u16*)take((size_t)MAXROWS * INTER_ * 2);
    int*   perm_rt = (int*)take((size_t)MAXROWS * 4);
    float* pw_rt   = (float*)take((size_t)MAXROWS * 4);
    int*   perm_sh = (int*)take((size_t)TTOK * 4);
    int*   topi    = (int*)take((size_t)TTOK * 2 * 4);
    float* topw    = (float*)take((size_t)TTOK * 2 * 4);
    int*   misc    = (int*)take(1024);
    int*   zrow    = (int*)take(4096);
    const size_t nW  = (size_t)NEXP * INTER_ * DIM_;     // w1 / w2 / w3 each
    const size_t nSW = (size_t)SINTER_ * DIM_;           // sw1 / sw2 / sw3 each
    u16* w1b  = (u16*)take(nW * 2);
    u16* w2b  = (u16*)take(nW * 2);
    u16* w3b  = (u16*)take(nW * 2);
    u16* sw1b = (u16*)take(nSW * 2);
    u16* sw2b = (u16*)take(nSW * 2);
    u16* sw3b = (u16*)take(nSW * 2);

    init_kernel<<<MAXROWS / 256, 256, 0, stream>>>(perm_rt, pw_rt, perm_sh, misc, zrow);
    cvt_kernel<<<2048, 256, 0, stream>>>(x, xb, TTOK * DIM_ / 8);
    gate_kernel<<<TTOK, 64, 0, stream>>>(x, gw, topi, topw, misc);
    scan_kernel<<<1, 1, 0, stream>>>(misc);
    scatter_kernel<<<TTOK / 256, 256, 0, stream>>>(topi, topw, misc, perm_rt, pw_rt);

    // weight conversion passes (HBM-bound; 4096 blocks to saturate)
    cvt_kernel<<<4096, 256, 0, stream>>>(w1,  w1b,  (int)(nW / 8));
    cvt_kernel<<<4096, 256, 0, stream>>>(w2,  w2b,  (int)(nW / 8));
    cvt_kernel<<<4096, 256, 0, stream>>>(w3,  w3b,  (int)(nW / 8));
    cvt_kernel<<<4096, 256, 0, stream>>>(sw1, sw1b, (int)(nSW / 8));
    cvt_kernel<<<4096, 256, 0, stream>>>(sw2, sw2b, (int)(nSW / 8));
    cvt_kernel<<<4096, 256, 0, stream>>>(sw3, sw3b, (int)(nSW / 8));

    auto grid8 = [](int total) { return ((total + 7) / 8) * 8; };
    auto chunk8 = [](int total) { return (total + 7) / 8; };

    // shared expert
    {
        int total = (TTOK / BM) * (SINTER_ / BN);
        gemm_h13_k<false><<<grid8(total), 256, 0, stream>>>(
            xb, sw1b, sw3b, hbuf, perm_sh, nullptr, nullptr, (const u16*)zrow,
            SINTER_, DIM_, TTOK / BM, chunk8(total));
    }
    {
        int total = (TTOK / BM) * (DIM_ / BN);
        gemm_out_k<false><<<grid8(total), 256, 0, stream>>>(
            hbuf, sw2b, out, nullptr, nullptr, nullptr, nullptr,
            SINTER_, TTOK / BM, chunk8(total));
    }
    // routed experts
    {
        int total = MAXMT * (INTER_ / BN);
        gemm_h13_k<true><<<grid8(total), 256, 0, stream>>>(
            xb, w1b, w3b, hbuf, perm_rt, misc + 48, misc + 128, (const u16*)zrow,
            INTER_, DIM_, MAXMT, chunk8(total));
    }
    {
        int total = MAXMT * (DIM_ / BN);
        gemm_out_k<true><<<grid8(total), 256, 0, stream>>>(
            hbuf, w2b, out, perm_rt, pw_rt, misc + 48, misc + 128,
            INTER_, MAXMT, chunk8(total));
    }
}